// Round 2
// baseline (61.833 us; speedup 1.0000x reference)
//
#include <hip/hip_runtime.h>

#define FEAT   41024
#define NF4    (FEAT / 4)     // 10256 float4 per row
#define HALF4  (NF4 / 2)      // 5128 float4 per half-row
#define NROWS  512
#define NBLK   (NROWS * 2)    // 1024 blocks, one per half-row

// ---------------------------------------------------------------------------
// Fused kernel: 1024 blocks each compute a half-row dot product (20512 floats)
// of the two 256x41024 matvecs. The last block to finish (atomic counter)
// assembles h = relu(W@x + b) for all 512 rows and runs the 512->32->32->1 MLP.
// ---------------------------------------------------------------------------
__global__ __launch_bounds__(256) void halfkp_fused(
    const float* __restrict__ x,
    const float* __restrict__ W_my,  const float* __restrict__ b_my,
    const float* __restrict__ W_opp, const float* __restrict__ b_opp,
    const float* __restrict__ W1, const float* __restrict__ b1,
    const float* __restrict__ W2, const float* __restrict__ b2,
    const float* __restrict__ W3, const float* __restrict__ b3,
    float* __restrict__ partial,   // ws: [NBLK] floats
    int*   __restrict__ counter,   // ws + 4096, zeroed each launch
    float* __restrict__ out)
{
    const int b    = blockIdx.x;
    const int tid  = threadIdx.x;
    const int row  = b >> 1;      // 0..511
    const int half = b & 1;       // which half of the 41024-long row

    const float4* __restrict__ W4 =
        (const float4*)(row < 256 ? W_my : W_opp)
        + (size_t)(row & 255) * NF4 + (size_t)half * HALF4;
    const float4* __restrict__ x4 =
        (const float4*)x + (row < 256 ? 0 : NF4) + (size_t)half * HALF4;

    // 5128 float4s / 256 threads = 20 each + 8 remainder.
    // Unroll 4 with independent accumulators -> >=4 outstanding HBM loads/wave.
    float a0 = 0.f, a1 = 0.f, a2 = 0.f, a3 = 0.f;
    int i = tid;
    #pragma unroll
    for (int k = 0; k < 5; ++k) {
        float4 w0 = W4[i      ]; float4 v0 = x4[i      ];
        float4 w1 = W4[i + 256]; float4 v1 = x4[i + 256];
        float4 w2 = W4[i + 512]; float4 v2 = x4[i + 512];
        float4 w3 = W4[i + 768]; float4 v3 = x4[i + 768];
        a0 += w0.x*v0.x + w0.y*v0.y + w0.z*v0.z + w0.w*v0.w;
        a1 += w1.x*v1.x + w1.y*v1.y + w1.z*v1.z + w1.w*v1.w;
        a2 += w2.x*v2.x + w2.y*v2.y + w2.z*v2.z + w2.w*v2.w;
        a3 += w3.x*v3.x + w3.y*v3.y + w3.z*v3.z + w3.w*v3.w;
        i += 1024;
    }
    if (tid < 8) {  // remainder float4 indices 5120..5127
        float4 w = W4[5120 + tid]; float4 v = x4[5120 + tid];
        a0 += w.x*v.x + w.y*v.y + w.z*v.z + w.w*v.w;
    }

    float acc = (a0 + a1) + (a2 + a3);
    #pragma unroll
    for (int off = 32; off > 0; off >>= 1)
        acc += __shfl_down(acc, off, 64);

    __shared__ float red[4];
    if ((tid & 63) == 0) red[tid >> 6] = acc;
    __syncthreads();

    __shared__ int lastflag;
    if (tid == 0) {
        float p = red[0] + red[1] + red[2] + red[3];
        // agent-scope store so other XCDs' last-block read is coherent
        __hip_atomic_store(&partial[b], p, __ATOMIC_RELAXED,
                           __HIP_MEMORY_SCOPE_AGENT);
        int old = __hip_atomic_fetch_add(counter, 1, __ATOMIC_ACQ_REL,
                                         __HIP_MEMORY_SCOPE_AGENT);
        lastflag = (old == NBLK - 1);
    }
    __syncthreads();
    if (!lastflag) return;

    // ------------------- last block: h assembly + MLP head -------------------
    __shared__ float hs[512];
    __shared__ float h1[32];
    __shared__ float h2[32];

    for (int r = tid; r < 512; r += 256) {
        float p0 = __hip_atomic_load(&partial[2*r],     __ATOMIC_ACQUIRE,
                                     __HIP_MEMORY_SCOPE_AGENT);
        float p1 = __hip_atomic_load(&partial[2*r + 1], __ATOMIC_ACQUIRE,
                                     __HIP_MEMORY_SCOPE_AGENT);
        float bias = (r < 256) ? b_my[r] : b_opp[r - 256];
        float s = p0 + p1 + bias;
        hs[r] = s > 0.f ? s : 0.f;
    }
    __syncthreads();

    // layer 1: 32 outputs, 8 threads per output, 64 elems each
    {
        const int o = tid >> 3;   // 0..31
        const int j = tid & 7;    // 0..7
        float acc1 = 0.f;
        const float* __restrict__ w = W1 + o * 512 + j * 64;
        #pragma unroll 8
        for (int k = 0; k < 64; ++k)
            acc1 += w[k] * hs[j * 64 + k];
        acc1 += __shfl_down(acc1, 4, 64);
        acc1 += __shfl_down(acc1, 2, 64);
        acc1 += __shfl_down(acc1, 1, 64);
        if (j == 0) {
            float s = acc1 + b1[o];
            h1[o] = s > 0.f ? s : 0.f;
        }
    }
    __syncthreads();

    // layer 2: 32 outputs, one thread each
    if (tid < 32) {
        float s = b2[tid];
        #pragma unroll 8
        for (int k = 0; k < 32; ++k)
            s += W2[tid * 32 + k] * h1[k];
        h2[tid] = s > 0.f ? s : 0.f;
    }
    __syncthreads();

    // layer 3: scalar
    if (tid == 0) {
        float s = b3[0];
        #pragma unroll 8
        for (int k = 0; k < 32; ++k)
            s += W3[k] * h2[k];
        out[0] = s;
    }
}

extern "C" void kernel_launch(void* const* d_in, const int* in_sizes, int n_in,
                              void* d_out, int out_size, void* d_ws, size_t ws_size,
                              hipStream_t stream)
{
    const float* x     = (const float*)d_in[0];
    const float* W_my  = (const float*)d_in[1];
    const float* b_my  = (const float*)d_in[2];
    const float* W_opp = (const float*)d_in[3];
    const float* b_opp = (const float*)d_in[4];
    const float* W1    = (const float*)d_in[5];
    const float* b1    = (const float*)d_in[6];
    const float* W2    = (const float*)d_in[7];
    const float* b2    = (const float*)d_in[8];
    const float* W3    = (const float*)d_in[9];
    const float* b3    = (const float*)d_in[10];

    float* out     = (float*)d_out;
    float* partial = (float*)d_ws;                    // 1024 floats
    int*   counter = (int*)((char*)d_ws + 4096);      // 1 int

    // zero the completion counter every launch (graph-capture-safe)
    hipMemsetAsync(counter, 0, sizeof(int), stream);

    halfkp_fused<<<NBLK, 256, 0, stream>>>(
        x, W_my, b_my, W_opp, b_opp,
        W1, b1, W2, b2, W3, b3,
        partial, counter, out);
}

// Round 3
// 23.989 us; speedup vs baseline: 2.5775x; 2.5775x over previous
//
#include <hip/hip_runtime.h>

#define FEAT 41024
#define NF4  (FEAT / 4)   // 10256 float4s per row = 40*256 + 16

// ---------------------------------------------------------------------------
// Kernel 1: the two 256x41024 matvecs + bias + ReLU, fused.
// One block per output row. 256 threads, float4 loads, 4 independent
// accumulators (8 outstanding 16B loads per wave) to saturate HBM.
// ---------------------------------------------------------------------------
__global__ __launch_bounds__(256) void halfkp_matvec(
    const float* __restrict__ x,
    const float* __restrict__ W_my,  const float* __restrict__ b_my,
    const float* __restrict__ W_opp, const float* __restrict__ b_opp,
    float* __restrict__ h)
{
    const int row = blockIdx.x;
    const int tid = threadIdx.x;

    const float4* __restrict__ W4 =
        (const float4*)(row < 256 ? W_my : W_opp) + (size_t)(row & 255) * NF4;
    const float4* __restrict__ x4 =
        (const float4*)x + (row < 256 ? 0 : NF4);
    const float bias = (row < 256) ? b_my[row] : b_opp[row - 256];

    float a0 = 0.f, a1 = 0.f, a2 = 0.f, a3 = 0.f;
    int i = tid;
    // 10 outer iters x 4 slices x 256 threads = 10240 float4s
    #pragma unroll
    for (int k = 0; k < 10; ++k) {
        float4 w0 = W4[i      ]; float4 v0 = x4[i      ];
        float4 w1 = W4[i + 256]; float4 v1 = x4[i + 256];
        float4 w2 = W4[i + 512]; float4 v2 = x4[i + 512];
        float4 w3 = W4[i + 768]; float4 v3 = x4[i + 768];
        a0 += w0.x*v0.x + w0.y*v0.y + w0.z*v0.z + w0.w*v0.w;
        a1 += w1.x*v1.x + w1.y*v1.y + w1.z*v1.z + w1.w*v1.w;
        a2 += w2.x*v2.x + w2.y*v2.y + w2.z*v2.z + w2.w*v2.w;
        a3 += w3.x*v3.x + w3.y*v3.y + w3.z*v3.z + w3.w*v3.w;
        i += 1024;
    }
    if (tid < 16) {  // remainder float4 indices 10240..10255
        float4 w = W4[10240 + tid]; float4 v = x4[10240 + tid];
        a0 += w.x*v.x + w.y*v.y + w.z*v.z + w.w*v.w;
    }

    float acc = (a0 + a1) + (a2 + a3);
    #pragma unroll
    for (int off = 32; off > 0; off >>= 1)
        acc += __shfl_down(acc, off, 64);

    __shared__ float red[4];
    if ((tid & 63) == 0) red[tid >> 6] = acc;
    __syncthreads();

    if (tid == 0) {
        float s = red[0] + red[1] + red[2] + red[3] + bias;
        h[row] = s > 0.f ? s : 0.f;
    }
}

// ---------------------------------------------------------------------------
// Kernel 2: trailing MLP 512 -> 32 -> 32 -> 1 (relu, relu, linear).
// Single block, 256 threads.
// ---------------------------------------------------------------------------
__global__ __launch_bounds__(256) void mlp_head(
    const float* __restrict__ h,
    const float* __restrict__ W1, const float* __restrict__ b1,
    const float* __restrict__ W2, const float* __restrict__ b2,
    const float* __restrict__ W3, const float* __restrict__ b3,
    float* __restrict__ out)
{
    __shared__ float hs[512];
    __shared__ float h1[32];
    __shared__ float h2[32];

    const int tid = threadIdx.x;
    hs[tid]       = h[tid];
    hs[tid + 256] = h[tid + 256];
    __syncthreads();

    // layer 1: 32 outputs, 8 threads per output, 64 elems per thread
    const int o = tid >> 3;
    const int j = tid & 7;
    float acc = 0.f;
    const float* __restrict__ w = W1 + o * 512 + j * 64;
    #pragma unroll 8
    for (int k = 0; k < 64; ++k)
        acc += w[k] * hs[j * 64 + k];
    acc += __shfl_down(acc, 4, 64);
    acc += __shfl_down(acc, 2, 64);
    acc += __shfl_down(acc, 1, 64);
    if (j == 0) {
        float s = acc + b1[o];
        h1[o] = s > 0.f ? s : 0.f;
    }
    __syncthreads();

    // layer 2: 32 outputs, one thread each
    if (tid < 32) {
        float s = b2[tid];
        #pragma unroll 8
        for (int k = 0; k < 32; ++k)
            s += W2[tid * 32 + k] * h1[k];
        h2[tid] = s > 0.f ? s : 0.f;
    }
    __syncthreads();

    // layer 3: scalar output
    if (tid == 0) {
        float s = b3[0];
        #pragma unroll 8
        for (int k = 0; k < 32; ++k)
            s += W3[k] * h2[k];
        out[0] = s;
    }
}

extern "C" void kernel_launch(void* const* d_in, const int* in_sizes, int n_in,
                              void* d_out, int out_size, void* d_ws, size_t ws_size,
                              hipStream_t stream)
{
    const float* x     = (const float*)d_in[0];
    const float* W_my  = (const float*)d_in[1];
    const float* b_my  = (const float*)d_in[2];
    const float* W_opp = (const float*)d_in[3];
    const float* b_opp = (const float*)d_in[4];
    const float* W1    = (const float*)d_in[5];
    const float* b1    = (const float*)d_in[6];
    const float* W2    = (const float*)d_in[7];
    const float* b2    = (const float*)d_in[8];
    const float* W3    = (const float*)d_in[9];
    const float* b3    = (const float*)d_in[10];

    float* out = (float*)d_out;
    float* h   = (float*)d_ws;   // 512 floats of scratch

    halfkp_matvec<<<512, 256, 0, stream>>>(x, W_my, b_my, W_opp, b_opp, h);
    mlp_head<<<1, 256, 0, stream>>>(h, W1, b1, W2, b2, W3, b3, out);
}

// Round 4
// 22.422 us; speedup vs baseline: 2.7577x; 1.0699x over previous
//
#include <hip/hip_runtime.h>

#define FEAT  41024
#define NF4   (FEAT / 4)    // 10256 float4s per full row
#define HALF4 (NF4 / 2)     // 5128 float4s per half-row = 256*20 + 8
#define NBLK  1024          // one block per half-row

// ---------------------------------------------------------------------------
// Kernel 1: half-row partial dot products of the two 256x41024 matvecs.
// 1024 blocks x 256 threads (4 blocks/CU), float4 loads, 4 independent
// accumulators. Plain stores of partials; kernel boundary = sync.
// ---------------------------------------------------------------------------
__global__ __launch_bounds__(256) void halfkp_matvec_part(
    const float* __restrict__ x,
    const float* __restrict__ W_my,
    const float* __restrict__ W_opp,
    float* __restrict__ partial)
{
    const int b    = blockIdx.x;
    const int tid  = threadIdx.x;
    const int row  = b >> 1;
    const int half = b & 1;

    const float4* __restrict__ W4 =
        (const float4*)(row < 256 ? W_my : W_opp)
        + (size_t)(row & 255) * NF4 + (size_t)half * HALF4;
    const float4* __restrict__ x4 =
        (const float4*)x + (row < 256 ? 0 : NF4) + (size_t)half * HALF4;

    float a0 = 0.f, a1 = 0.f, a2 = 0.f, a3 = 0.f;
    int i = tid;
    #pragma unroll
    for (int k = 0; k < 5; ++k) {   // 5 iters x 4 slices x 256 thr = 5120 f4
        float4 w0 = W4[i      ]; float4 v0 = x4[i      ];
        float4 w1 = W4[i + 256]; float4 v1 = x4[i + 256];
        float4 w2 = W4[i + 512]; float4 v2 = x4[i + 512];
        float4 w3 = W4[i + 768]; float4 v3 = x4[i + 768];
        a0 += w0.x*v0.x + w0.y*v0.y + w0.z*v0.z + w0.w*v0.w;
        a1 += w1.x*v1.x + w1.y*v1.y + w1.z*v1.z + w1.w*v1.w;
        a2 += w2.x*v2.x + w2.y*v2.y + w2.z*v2.z + w2.w*v2.w;
        a3 += w3.x*v3.x + w3.y*v3.y + w3.z*v3.z + w3.w*v3.w;
        i += 1024;
    }
    if (tid < 8) {  // remainder f4 indices 5120..5127
        float4 w = W4[5120 + tid]; float4 v = x4[5120 + tid];
        a0 += w.x*v.x + w.y*v.y + w.z*v.z + w.w*v.w;
    }

    float acc = (a0 + a1) + (a2 + a3);
    #pragma unroll
    for (int off = 32; off > 0; off >>= 1)
        acc += __shfl_down(acc, off, 64);

    __shared__ float red[4];
    if ((tid & 63) == 0) red[tid >> 6] = acc;
    __syncthreads();
    if (tid == 0)
        partial[b] = red[0] + red[1] + red[2] + red[3];
}

// ---------------------------------------------------------------------------
// Kernel 2: assemble h = relu(partials + bias), then MLP 512->32->32->1.
// One block x 1024 threads. W1 preloaded into registers before the partial
// reduction so the HBM latencies overlap. Strided W1/hs access: coalesced
// global, broadcast LDS.
// ---------------------------------------------------------------------------
__global__ __launch_bounds__(1024) void mlp_head(
    const float* __restrict__ partial,
    const float* __restrict__ b_my, const float* __restrict__ b_opp,
    const float* __restrict__ W1,  const float* __restrict__ b1,
    const float* __restrict__ W2,  const float* __restrict__ b2,
    const float* __restrict__ W3,  const float* __restrict__ b3,
    float* __restrict__ out)
{
    __shared__ float hs[512];
    __shared__ float h1[32];
    __shared__ float h2[32];

    const int tid = threadIdx.x;
    const int o = tid >> 5;   // 0..31  (W1 output row)
    const int j = tid & 31;   // 0..31  (lane within the row-group)

    // preload W1 slice into registers (independent of partials)
    float w[16];
    #pragma unroll
    for (int k = 0; k < 16; ++k)
        w[k] = W1[o * 512 + j + 32 * k];

    // assemble h
    if (tid < 512) {
        float p0 = partial[2 * tid];
        float p1 = partial[2 * tid + 1];
        float bias = (tid < 256) ? b_my[tid] : b_opp[tid - 256];
        float s = p0 + p1 + bias;
        hs[tid] = s > 0.f ? s : 0.f;
    }
    __syncthreads();

    // layer 1: 32 outputs, 32 lanes each
    float acc = 0.f;
    #pragma unroll
    for (int k = 0; k < 16; ++k)
        acc += w[k] * hs[j + 32 * k];
    acc += __shfl_down(acc, 16, 32);
    acc += __shfl_down(acc,  8, 32);
    acc += __shfl_down(acc,  4, 32);
    acc += __shfl_down(acc,  2, 32);
    acc += __shfl_down(acc,  1, 32);
    if (j == 0) {
        float s = acc + b1[o];
        h1[o] = s > 0.f ? s : 0.f;
    }
    __syncthreads();

    // layer 2: 32 outputs, one thread each
    if (tid < 32) {
        float s = b2[tid];
        #pragma unroll 8
        for (int k = 0; k < 32; ++k)
            s += W2[tid * 32 + k] * h1[k];
        h2[tid] = s > 0.f ? s : 0.f;
    }
    __syncthreads();

    // layer 3: scalar
    if (tid == 0) {
        float s = b3[0];
        #pragma unroll 8
        for (int k = 0; k < 32; ++k)
            s += W3[k] * h2[k];
        out[0] = s;
    }
}

extern "C" void kernel_launch(void* const* d_in, const int* in_sizes, int n_in,
                              void* d_out, int out_size, void* d_ws, size_t ws_size,
                              hipStream_t stream)
{
    const float* x     = (const float*)d_in[0];
    const float* W_my  = (const float*)d_in[1];
    const float* b_my  = (const float*)d_in[2];
    const float* W_opp = (const float*)d_in[3];
    const float* b_opp = (const float*)d_in[4];
    const float* W1    = (const float*)d_in[5];
    const float* b1    = (const float*)d_in[6];
    const float* W2    = (const float*)d_in[7];
    const float* b2    = (const float*)d_in[8];
    const float* W3    = (const float*)d_in[9];
    const float* b3    = (const float*)d_in[10];

    float* out     = (float*)d_out;
    float* partial = (float*)d_ws;   // 1024 floats

    halfkp_matvec_part<<<NBLK, 256, 0, stream>>>(x, W_my, W_opp, partial);
    mlp_head<<<1, 1024, 0, stream>>>(partial, b_my, b_opp,
                                     W1, b1, W2, b2, W3, b3, out);
}